// Round 1
// baseline (130.365 us; speedup 1.0000x reference)
//
#include <hip/hip_runtime.h>

// WeightedChamferDistanceL2 on MI355X (gfx950).
// B=4; partial: [B,2048,3], infer: [B,8192,3], complete: [B,8192,3], out: scalar f32.
//
// dist_cp[b,m] = min_p |complete[b,m]-partial[b,p]|^2      (task 0)
// dist_ic[b,n] = min_m |infer[b,n]-complete[b,m]|^2        (task 1)
// dist_ci[b,m] = min_n |complete[b,m]-infer[b,n]|^2        (task 2)
// out = mean(dist_ic) + mean(dist_cp*dist_ci)/max(dist_cp)
//
// Inner loop uses d = |q|^2 + |c|^2 - 2 q.c with candidates pre-packed as
// (2cx,2cy,2cz,|c|^2) in LDS; |q|^2 hoisted out of the min -> 3 FMA + 1 min
// per pair (min3-fusable). Cross-chunk combine via order-preserving-uint
// atomicMin. ws usage: 3 * 4*8192 u32 keys = 384 KiB.

#define BATCH   4
#define NP      2048
#define NQ      8192           // infer & complete per-batch counts
#define CHUNK   1024           // candidates per block
#define THREADS 256

__device__ __forceinline__ unsigned int orderKey(float f) {
    unsigned int u = __float_as_uint(f);
    return (u & 0x80000000u) ? ~u : (u | 0x80000000u);
}
__device__ __forceinline__ float keyToFloat(unsigned int k) {
    unsigned int u = (k & 0x80000000u) ? (k ^ 0x80000000u) : ~k;
    return __uint_as_float(u);
}

__global__ __launch_bounds__(THREADS) void minDistKernel(
    const float* __restrict__ partial,
    const float* __restrict__ infer,
    const float* __restrict__ complete,
    unsigned int* __restrict__ keys)   // [3][BATCH*NQ]: cp, ic, ci
{
    __shared__ float4 tile[CHUNK];     // 16 KiB: packed candidates (2x,2y,2z,|c|^2)

    const int b = blockIdx.y;
    const int z = blockIdx.z;
    int task, chunk;
    if (z < 2)       { task = 0; chunk = z; }        // partial: 2048 = 2 chunks
    else if (z < 10) { task = 1; chunk = z - 2; }    // complete: 8 chunks
    else             { task = 2; chunk = z - 10; }   // infer: 8 chunks

    const float* qraw;
    const float* craw;
    unsigned int* kout;
    if (task == 0)      { qraw = complete + b*NQ*3; craw = partial  + b*NP*3; kout = keys + 0*BATCH*NQ + b*NQ; }
    else if (task == 1) { qraw = infer    + b*NQ*3; craw = complete + b*NQ*3; kout = keys + 1*BATCH*NQ + b*NQ; }
    else                { qraw = complete + b*NQ*3; craw = infer    + b*NQ*3; kout = keys + 2*BATCH*NQ + b*NQ; }

    const int tid = threadIdx.x;

    // Stage + pack this block's candidate chunk into LDS.
    for (int i = tid; i < CHUNK; i += THREADS) {
        const float* p = craw + (chunk*CHUNK + i)*3;
        float x = p[0], y = p[1], zc = p[2];
        tile[i] = make_float4(2.0f*x, 2.0f*y, 2.0f*zc, x*x + y*y + zc*zc);
    }

    // Two queries per thread (amortizes the broadcast LDS read).
    const int q0 = blockIdx.x*(2*THREADS) + tid;
    const int q1 = q0 + THREADS;
    const float ax = qraw[q0*3+0], ay = qraw[q0*3+1], az = qraw[q0*3+2];
    const float bx = qraw[q1*3+0], by = qraw[q1*3+1], bz = qraw[q1*3+2];

    __syncthreads();

    float m0 = __builtin_inff();
    float m1 = __builtin_inff();
    #pragma unroll 4
    for (int j = 0; j < CHUNK; j += 2) {
        float4 c0 = tile[j];
        float4 c1 = tile[j+1];
        float t00 = fmaf(-ax, c0.x, fmaf(-ay, c0.y, fmaf(-az, c0.z, c0.w)));
        float t01 = fmaf(-ax, c1.x, fmaf(-ay, c1.y, fmaf(-az, c1.z, c1.w)));
        m0 = fminf(m0, fminf(t00, t01));           // -> v_min3_f32
        float t10 = fmaf(-bx, c0.x, fmaf(-by, c0.y, fmaf(-bz, c0.z, c0.w)));
        float t11 = fmaf(-bx, c1.x, fmaf(-by, c1.y, fmaf(-bz, c1.z, c1.w)));
        m1 = fminf(m1, fminf(t10, t11));
    }

    const float d0 = fmaf(ax, ax, fmaf(ay, ay, az*az)) + m0;
    const float d1 = fmaf(bx, bx, fmaf(by, by, bz*bz)) + m1;
    atomicMin(&kout[q0], orderKey(d0));
    atomicMin(&kout[q1], orderKey(d1));
}

__global__ __launch_bounds__(1024) void reduceKernel(
    const unsigned int* __restrict__ keys, float* __restrict__ out)
{
    __shared__ float red[1024];
    const int tid = threadIdx.x;
    const int N = BATCH*NQ; // 32768
    const unsigned int* kcp = keys;
    const unsigned int* kic = keys + N;
    const unsigned int* kci = keys + 2*N;

    float mx   = -__builtin_inff();
    float s_ic = 0.0f;
    float s_w  = 0.0f;
    for (int i = tid; i < N; i += 1024) {
        float dcp = keyToFloat(kcp[i]);
        float dic = keyToFloat(kic[i]);
        float dci = keyToFloat(kci[i]);
        mx   = fmaxf(mx, dcp);
        s_ic += dic;
        s_w   = fmaf(dcp, dci, s_w);
    }

    red[tid] = mx; __syncthreads();
    for (int s = 512; s > 0; s >>= 1) {
        if (tid < s) red[tid] = fmaxf(red[tid], red[tid+s]);
        __syncthreads();
    }
    const float maxcp = red[0];
    __syncthreads();

    red[tid] = s_ic; __syncthreads();
    for (int s = 512; s > 0; s >>= 1) {
        if (tid < s) red[tid] += red[tid+s];
        __syncthreads();
    }
    const float sum_ic = red[0];
    __syncthreads();

    red[tid] = s_w; __syncthreads();
    for (int s = 512; s > 0; s >>= 1) {
        if (tid < s) red[tid] += red[tid+s];
        __syncthreads();
    }

    if (tid == 0) {
        const float sum_w = red[0];
        out[0] = sum_ic / (float)N + (sum_w / maxcp) / (float)N;
    }
}

extern "C" void kernel_launch(void* const* d_in, const int* in_sizes, int n_in,
                              void* d_out, int out_size, void* d_ws, size_t ws_size,
                              hipStream_t stream) {
    const float* partial  = (const float*)d_in[0];
    const float* infer    = (const float*)d_in[1];
    const float* complete = (const float*)d_in[2];
    unsigned int* keys = (unsigned int*)d_ws;

    // atomicMin identity: key 0xFFFFFFFF (ws is re-poisoned to 0xAA each call).
    hipMemsetAsync(keys, 0xFF, (size_t)3*BATCH*NQ*sizeof(unsigned int), stream);

    // grid: x = query tiles (8192 / 512), y = batch, z = task-chunk (2+8+8)
    minDistKernel<<<dim3(16, BATCH, 18), THREADS, 0, stream>>>(partial, infer, complete, keys);
    reduceKernel<<<1, 1024, 0, stream>>>(keys, (float*)d_out);
}

// Round 2
// 111.797 us; speedup vs baseline: 1.1661x; 1.1661x over previous
//
#include <hip/hip_runtime.h>

// WeightedChamferDistanceL2 on MI355X (gfx950) — round 2.
// B=4; partial: [B,2048,3], infer: [B,8192,3], complete: [B,8192,3], out: scalar f32.
//
// d = |q|^2 + |c|^2 - 2 q.c ; candidates pre-packed as (2cx,2cy,2cz,|c|^2) in
// LDS, |q|^2 hoisted out of the min -> 3 FMA + 0.5 min3 per pair.
// Round-2 changes vs round-1:
//   * 8 queries/thread (was 2): LDS broadcast-read bandwidth per VALU op cut
//     4x (was ~290 B/cyc/CU demanded vs 128 peak -> now ~73).
//   * CHUNK=128 -> 2304 uniform blocks (was 1152 w/ 1.1 blk/CU imbalance).
//   * reduce: 8 blocks + last-block combine (ticket counter), was 1 block.

#define BATCH   4
#define NP      2048
#define NQ      8192
#define CHUNK   128            // candidates per block
#define THREADS 256
#define QPT     8              // queries per thread
#define NTOT    (BATCH*NQ)     // 32768

__device__ __forceinline__ unsigned int orderKey(float f) {
    unsigned int u = __float_as_uint(f);
    return (u & 0x80000000u) ? ~u : (u | 0x80000000u);
}
__device__ __forceinline__ float keyToFloat(unsigned int k) {
    unsigned int u = (k & 0x80000000u) ? (k ^ 0x80000000u) : ~k;
    return __uint_as_float(u);
}

__global__ __launch_bounds__(THREADS) void minDistKernel(
    const float* __restrict__ partial,
    const float* __restrict__ infer,
    const float* __restrict__ complete,
    unsigned int* __restrict__ keys)   // [3][NTOT]: cp, ic, ci
{
    __shared__ float4 tile[CHUNK];     // 2 KiB packed candidates (2x,2y,2z,|c|^2)

    const int b = blockIdx.y;
    const int z = blockIdx.z;
    int task, chunk;
    if (z < 16)      { task = 0; chunk = z; }        // partial: 2048/128 = 16 chunks
    else if (z < 80) { task = 1; chunk = z - 16; }   // complete: 64 chunks
    else             { task = 2; chunk = z - 80; }   // infer:    64 chunks

    const float* qraw;
    const float* craw;
    unsigned int* kout;
    if (task == 0)      { qraw = complete + b*NQ*3; craw = partial  + b*NP*3; kout = keys + 0*NTOT + b*NQ; }
    else if (task == 1) { qraw = infer    + b*NQ*3; craw = complete + b*NQ*3; kout = keys + 1*NTOT + b*NQ; }
    else                { qraw = complete + b*NQ*3; craw = infer    + b*NQ*3; kout = keys + 2*NTOT + b*NQ; }

    const int tid = threadIdx.x;

    if (tid < CHUNK) {
        const float* p = craw + (chunk*CHUNK + tid)*3;
        float x = p[0], y = p[1], zc = p[2];
        tile[tid] = make_float4(2.0f*x, 2.0f*y, 2.0f*zc, x*x + y*y + zc*zc);
    }

    // 8 queries per thread, stride-256 so global loads stay coalesced.
    const int qbase = blockIdx.x*(QPT*THREADS) + tid;
    float nx[QPT], ny[QPT], nz[QPT], mn[QPT];
    #pragma unroll
    for (int q = 0; q < QPT; ++q) {
        const float* p = qraw + (qbase + q*THREADS)*3;
        nx[q] = -p[0]; ny[q] = -p[1]; nz[q] = -p[2];
        mn[q] = __builtin_inff();
    }

    __syncthreads();

    for (int j = 0; j < CHUNK; j += 4) {
        float4 c0 = tile[j+0];
        float4 c1 = tile[j+1];
        float4 c2 = tile[j+2];
        float4 c3 = tile[j+3];
        #pragma unroll
        for (int q = 0; q < QPT; ++q) {
            float t0 = fmaf(nx[q], c0.x, fmaf(ny[q], c0.y, fmaf(nz[q], c0.z, c0.w)));
            float t1 = fmaf(nx[q], c1.x, fmaf(ny[q], c1.y, fmaf(nz[q], c1.z, c1.w)));
            float t2 = fmaf(nx[q], c2.x, fmaf(ny[q], c2.y, fmaf(nz[q], c2.z, c2.w)));
            float t3 = fmaf(nx[q], c3.x, fmaf(ny[q], c3.y, fmaf(nz[q], c3.z, c3.w)));
            mn[q] = fminf(mn[q], fminf(t0, t1));   // -> v_min3_f32
            mn[q] = fminf(mn[q], fminf(t2, t3));
        }
    }

    #pragma unroll
    for (int q = 0; q < QPT; ++q) {
        float sq = fmaf(nx[q], nx[q], fmaf(ny[q], ny[q], nz[q]*nz[q]));
        atomicMin(&kout[qbase + q*THREADS], orderKey(sq + mn[q]));
    }
}

__global__ __launch_bounds__(256) void reduceKernel(
    unsigned int* __restrict__ ws, float* __restrict__ out)
{
    const unsigned int* kcp = ws;
    const unsigned int* kic = ws + NTOT;
    const unsigned int* kci = ws + 2*NTOT;
    unsigned int* counter = ws + 3*NTOT;
    float* parts = (float*)(ws + 3*NTOT + 1);   // [3][8]: max, s1, s2 per block

    const int tid = threadIdx.x;
    const int base = blockIdx.x * (NTOT/8);     // 4096 per block

    float mx = -__builtin_inff();
    float s1 = 0.0f, s2 = 0.0f;
    #pragma unroll 4
    for (int k = 0; k < NTOT/8/256; ++k) {      // 16 iters
        int i = base + k*256 + tid;
        float dcp = keyToFloat(kcp[i]);
        float dic = keyToFloat(kic[i]);
        float dci = keyToFloat(kci[i]);
        mx = fmaxf(mx, dcp);
        s1 += dic;
        s2 = fmaf(dcp, dci, s2);
    }

    #pragma unroll
    for (int off = 32; off > 0; off >>= 1) {
        mx = fmaxf(mx, __shfl_down(mx, off));
        s1 += __shfl_down(s1, off);
        s2 += __shfl_down(s2, off);
    }

    __shared__ float smx[4], ss1[4], ss2[4];
    const int wid = tid >> 6, lane = tid & 63;
    if (lane == 0) { smx[wid] = mx; ss1[wid] = s1; ss2[wid] = s2; }
    __syncthreads();

    if (tid == 0) {
        mx = fmaxf(fmaxf(smx[0], smx[1]), fmaxf(smx[2], smx[3]));
        s1 = (ss1[0] + ss1[1]) + (ss1[2] + ss1[3]);
        s2 = (ss2[0] + ss2[1]) + (ss2[2] + ss2[3]);
        const int bi = blockIdx.x;
        parts[bi] = mx; parts[8 + bi] = s1; parts[16 + bi] = s2;
        __threadfence();                         // release partials (device scope)
        unsigned int old = atomicAdd(counter, 1u);
        if (old == gridDim.x - 1) {              // last arriver combines
            __threadfence();                     // acquire
            const volatile float* vp = (const volatile float*)parts;
            float M = vp[0], S1 = 0.0f, S2 = 0.0f;
            for (int i = 1; i < 8; ++i) M = fmaxf(M, vp[i]);
            for (int i = 0; i < 8; ++i) { S1 += vp[8 + i]; S2 += vp[16 + i]; }
            out[0] = S1 / (float)NTOT + S2 / (M * (float)NTOT);
        }
    }
}

extern "C" void kernel_launch(void* const* d_in, const int* in_sizes, int n_in,
                              void* d_out, int out_size, void* d_ws, size_t ws_size,
                              hipStream_t stream) {
    const float* partial  = (const float*)d_in[0];
    const float* infer    = (const float*)d_in[1];
    const float* complete = (const float*)d_in[2];
    unsigned int* keys = (unsigned int*)d_ws;

    // keys -> 0xFFFFFFFF (atomicMin identity); ticket counter -> 0.
    hipMemsetAsync(keys, 0xFF, (size_t)3*NTOT*sizeof(unsigned int), stream);
    hipMemsetAsync(keys + 3*NTOT, 0, sizeof(unsigned int), stream);

    // grid: x = query tiles (8192 / 2048), y = batch, z = task-chunks (16+64+64)
    minDistKernel<<<dim3(4, BATCH, 144), THREADS, 0, stream>>>(partial, infer, complete, keys);
    reduceKernel<<<8, 256, 0, stream>>>(keys, (float*)d_out);
}